// Round 9
// baseline (1514.541 us; speedup 1.0000x reference)
//
#include <hip/hip_runtime.h>

// GRUModel: B=4096, H=512, V=512, T=31, D_IN=14
// d_out = [probs: 4096*31*512 f32][hidden: 4096*31*512 f32]
#define NTH 15872   // 31*512

typedef __bf16 bf16x8 __attribute__((ext_vector_type(8)));
typedef float  f32x4  __attribute__((ext_vector_type(4)));

__device__ __forceinline__ unsigned short f2bf(float f) {
    unsigned u = __float_as_uint(f);
    u = u + 0x7fffu + ((u >> 16) & 1u);
    return (unsigned short)(u >> 16);
}
__device__ __forceinline__ float sigm(float x)  { return 1.f / (1.f + __expf(-x)); }
__device__ __forceinline__ float tanhf_(float x){ return 2.f / (1.f + __expf(-2.f * x)) - 1.f; }

// R1-proven LDS tile layout (64B rows, K=32 bf16): chunk ^= (r>>1)&3.
__device__ __forceinline__ int lds_off(int r, int kb) {
    return r * 64 + ((kb ^ ((r >> 1) & 3)) << 4);
}
__device__ __forceinline__ int4 ldg16(const char* g0, int stride, int kbyte, int c) {
    int r = c >> 2, kb = c & 3;
    return *(const int4*)(g0 + (size_t)r * stride + kbyte + kb * 16);
}
__device__ __forceinline__ void sts16(char* lds, int c, int4 v) {
    int r = c >> 2, kb = c & 3;
    *(int4*)(lds + lds_off(r, kb)) = v;
}
__device__ __forceinline__ bf16x8 ldsfrag(const char* lds, int row, int hi) {
    return *(const bf16x8*)(lds + lds_off(row, hi));
}
// 128B-row layout (BK=64 bf16): chunk ^= (r&7). Write side: per 16-lane phase
// 2 rows x 8 chunks -> 2-way max (free, m136). Frag read (16 rows, fixed
// chunk): XOR spreads over 8 chunks -> 2-way per phase. R5-verified.
__device__ __forceinline__ int soff(int r, int kb) { return r * 128 + ((kb ^ (r & 7)) << 4); }

// load 8 f32 (stride in floats), round to bf16, pack to one 16B chunk
__device__ __forceinline__ int4 ldg16_f32(const float* g0, int stride, int koff, int c) {
    int r = c >> 2, kb = c & 3;
    const float4* p = (const float4*)(g0 + (size_t)r * stride + koff + kb * 8);
    float4 a = p[0], b = p[1];
    union { unsigned short us[8]; int4 v; } u;
    u.us[0]=f2bf(a.x); u.us[1]=f2bf(a.y); u.us[2]=f2bf(a.z); u.us[3]=f2bf(a.w);
    u.us[4]=f2bf(b.x); u.us[5]=f2bf(b.y); u.us[6]=f2bf(b.z); u.us[7]=f2bf(b.w);
    return u.v;
}

// ---------------------------------------------------------------- converts
__global__ void k_f32_to_bf16(const float* __restrict__ in,
                              unsigned short* __restrict__ out, int n4) {
    int i = blockIdx.x * 256 + threadIdx.x;
    if (i < n4) {
        float4 v = ((const float4*)in)[i];
        ushort4 o;
        o.x = f2bf(v.x); o.y = f2bf(v.y); o.z = f2bf(v.z); o.w = f2bf(v.w);
        ((ushort4*)out)[i] = o;
    }
}

// ---------------------------------------------------------------- x = inputs @ W_in.T + b_in  -> bf16
__global__ void k_linear_in(const float* __restrict__ inp,   // [4096,14]
                            const float* __restrict__ W,     // [512,14]
                            const float* __restrict__ bias,  // [512]
                            unsigned short* __restrict__ xb) // [4096,512] bf16
{
    int idx = blockIdx.x * 256 + threadIdx.x;   // b*512 + j
    int b = idx >> 9, j = idx & 511;
    const float* ir = inp + (size_t)b * 14;
    const float* wr = W + (size_t)j * 14;
    float acc = bias[j];
#pragma unroll
    for (int k = 0; k < 14; ++k) acc += ir[k] * wr[k];
    xb[idx] = f2bf(acc);
}

// ---------------------------------------------------------------- gi = x @ W_ih.T + b_ih (f32 out)
// R1-verbatim: BM=128, BN=64, BK=32, 256 thr = 4 waves (2x2), wave tile 64x32
__global__ __launch_bounds__(256) void k_gemm_gi(
    const unsigned short* __restrict__ A,   // [4096,512] bf16
    const unsigned short* __restrict__ W,   // [1536,512] bf16
    const float* __restrict__ bias,         // [1536]
    float* __restrict__ C)                  // [4096,1536]
{
    __shared__ __align__(16) char lA[128 * 64];
    __shared__ __align__(16) char lB[64 * 64];
    const int tid = threadIdx.x, lane = tid & 63, wid = tid >> 6;
    const int wm = wid >> 1, wn = wid & 1, hi = lane >> 4, c16 = lane & 15;
    const int m0 = blockIdx.x * 128, n0 = blockIdx.y * 64;
    const char* ga = (const char*)(A + (size_t)m0 * 512);
    const char* gb = (const char*)(W + (size_t)n0 * 512);
    f32x4 acc[4][2] = {};
    int4 ra0 = ldg16(ga, 1024, 0, tid);
    int4 ra1 = ldg16(ga, 1024, 0, tid + 256);
    int4 rb0 = ldg16(gb, 1024, 0, tid);
    for (int kt = 0; kt < 16; ++kt) {
        if (kt) __syncthreads();
        sts16(lA, tid, ra0); sts16(lA, tid + 256, ra1); sts16(lB, tid, rb0);
        __syncthreads();
        if (kt < 15) {
            int kb = (kt + 1) * 64;
            ra0 = ldg16(ga, 1024, kb, tid);
            ra1 = ldg16(ga, 1024, kb, tid + 256);
            rb0 = ldg16(gb, 1024, kb, tid);
        }
        bf16x8 af[4];
#pragma unroll
        for (int i = 0; i < 4; ++i) af[i] = ldsfrag(lA, wm * 64 + i * 16 + c16, hi);
#pragma unroll
        for (int j = 0; j < 2; ++j) {
            bf16x8 bfr = ldsfrag(lB, wn * 32 + j * 16 + c16, hi);
#pragma unroll
            for (int i = 0; i < 4; ++i)
                acc[i][j] = __builtin_amdgcn_mfma_f32_16x16x32_bf16(af[i], bfr, acc[i][j], 0, 0, 0);
        }
    }
#pragma unroll
    for (int i = 0; i < 4; ++i) {
        int m = m0 + wm * 64 + i * 16 + hi * 4;
#pragma unroll
        for (int j = 0; j < 2; ++j) {
            int n = n0 + wn * 32 + j * 16 + c16;
            float bj = bias[n];
#pragma unroll
            for (int q = 0; q < 4; ++q)
                C[(size_t)(m + q) * 1536 + n] = acc[i][j][q] + bj;
        }
    }
}

// ---------------------------------------------------------------- fused GRU step v4
// BM=128, BN=32/gate (grid 32x16 = 512 blocks -> 2 blocks/CU), BK=64,
// 256 thr = 4 waves (2wm x 2wn), wave tile 64 rows x 16 cols per gate.
// vs R8 (BK=32): barriers/step 32 -> 16; staging uniform (no divergence);
// k-order within each output's MFMA chain unchanged -> bitwise-identical.
__global__ __launch_bounds__(256) void k_step(
    const unsigned short* __restrict__ Hin, int hstride,  // elems
    const unsigned short* __restrict__ Whh,   // [1536,512] bf16
    const float* __restrict__ gi,             // [4096,1536]
    const float* __restrict__ bhh,            // [1536]
    float* __restrict__ hidden,               // [4096, 15872] f32 (d_out region)
    unsigned short* __restrict__ Hout, int ostride,       // elems
    int t)
{
    __shared__ __align__(16) char lA[128 * 128];   // 16 KB
    __shared__ __align__(16) char lB[96 * 128];    // 12 KB
    const int tid = threadIdx.x, lane = tid & 63, wid = tid >> 6;
    const int wm = wid >> 1, wn = wid & 1, hi = lane >> 4, c16 = lane & 15;
    const int m0 = blockIdx.x * 128, n0 = blockIdx.y * 32;
    f32x4 acc[3][4] = {};
    if (t > 0) {
        const char* ga = (const char*)(Hin + (size_t)m0 * hstride);
        const size_t gas = (size_t)hstride * 2;    // row stride bytes
        // A: 128 rows x 8 chunks = 1024 ; B: 96 rows x 8 = 768
        const char* pa[4]; int la[4];
#pragma unroll
        for (int s = 0; s < 4; ++s) {
            int c = tid + 256 * s, r = c >> 3, kb = c & 7;
            pa[s] = ga + (size_t)r * gas + kb * 16;
            la[s] = soff(r, kb);
        }
        const char* pb[3]; int lb[3];
#pragma unroll
        for (int s = 0; s < 3; ++s) {
            int c = tid + 256 * s, r = c >> 3, kb = c & 7;
            int wrow = ((r >> 5) << 9) + n0 + (r & 31);   // gate*512 + n0 + local
            pb[s] = (const char*)Whh + (size_t)wrow * 1024 + kb * 16;
            lb[s] = soff(r, kb);
        }
        int4 ra[4], rb[3];
#pragma unroll
        for (int s = 0; s < 4; ++s) ra[s] = *(const int4*)pa[s];
#pragma unroll
        for (int s = 0; s < 3; ++s) rb[s] = *(const int4*)pb[s];
        for (int kt = 0; kt < 8; ++kt) {
            if (kt) __syncthreads();
#pragma unroll
            for (int s = 0; s < 4; ++s) *(int4*)(lA + la[s]) = ra[s];
#pragma unroll
            for (int s = 0; s < 3; ++s) *(int4*)(lB + lb[s]) = rb[s];
            __syncthreads();
            if (kt < 7) {
                int o = (kt + 1) * 128;
#pragma unroll
                for (int s = 0; s < 4; ++s) ra[s] = *(const int4*)(pa[s] + o);
#pragma unroll
                for (int s = 0; s < 3; ++s) rb[s] = *(const int4*)(pb[s] + o);
            }
#pragma unroll
            for (int h = 0; h < 2; ++h) {
                bf16x8 af[4];
#pragma unroll
                for (int i = 0; i < 4; ++i)
                    af[i] = *(const bf16x8*)(lA + soff(wm * 64 + i * 16 + c16, h * 4 + hi));
#pragma unroll
                for (int g = 0; g < 3; ++g) {
                    bf16x8 bfr = *(const bf16x8*)(lB + soff(g * 32 + wn * 16 + c16, h * 4 + hi));
#pragma unroll
                    for (int i = 0; i < 4; ++i)
                        acc[g][i] = __builtin_amdgcn_mfma_f32_16x16x32_bf16(af[i], bfr, acc[g][i], 0, 0, 0);
                }
            }
        }
    }
    // epilogue: gate math (16 outputs/thread, r/z/n wave-local)
    const int n = n0 + wn * 16 + c16;              // gate-local column
    const float br = bhh[n], bz = bhh[512 + n], bn_ = bhh[1024 + n];
#pragma unroll
    for (int i = 0; i < 4; ++i) {
        int mB = m0 + wm * 64 + i * 16 + hi * 4;
#pragma unroll
        for (int q = 0; q < 4; ++q) {
            int m = mB + q;
            size_t gb0 = (size_t)m * 1536 + n;
            float pr = gi[gb0]        + acc[0][i][q] + br;
            float pz = gi[gb0 + 512]  + acc[1][i][q] + bz;
            float r  = sigm(pr);
            float z  = sigm(pz);
            float nn = tanhf_(gi[gb0 + 1024] + r * (acc[2][i][q] + bn_));
            float hold = (t > 0) ? hidden[(size_t)m * NTH + (size_t)(t - 1) * 512 + n] : 0.f;
            float hn = (1.f - z) * nn + z * hold;
            hidden[(size_t)m * NTH + (size_t)t * 512 + n] = hn;
            Hout[(size_t)m * ostride + n] = f2bf(hn);
        }
    }
}

// ---------------------------------------------------------------- projection + softmax (R4-verbatim)
// BM=64, BN=512 (full V), BK=32, 256 thr = 4 waves in 2x2; wave tile 32x256.
template<bool BF16A>
__global__ __launch_bounds__(256) void k_proj(
    const void* __restrict__ Aptr,          // bf16 or f32 [126976,512], row stride astr elems
    int astr,
    const unsigned short* __restrict__ Wo,  // [512,512] bf16
    const float* __restrict__ bo,
    float* __restrict__ out)                // [126976,512]
{
    __shared__ __align__(16) char lA[64 * 64];
    __shared__ __align__(16) char lB[512 * 64];
    __shared__ float red[2][2][32];
    const int tid = threadIdx.x, lane = tid & 63, wid = tid >> 6;
    const int wm = wid >> 1, wn = wid & 1, hi = lane >> 4, c16 = lane & 15;
    const int m0 = blockIdx.x * 64;
    const char*  gab = (const char*)Aptr  + (size_t)m0 * astr * 2;
    const float* gaf = (const float*)Aptr + (size_t)m0 * astr;
    const char*  gb  = (const char*)Wo;
    f32x4 acc[2][16] = {};
    int4 ra = BF16A ? ldg16(gab, astr * 2, 0, tid) : ldg16_f32(gaf, astr, 0, tid);
    int4 rb[8];
#pragma unroll
    for (int s = 0; s < 8; ++s) rb[s] = ldg16(gb, 1024, 0, tid + 256 * s);
    for (int kt = 0; kt < 16; ++kt) {
        if (kt) __syncthreads();
        sts16(lA, tid, ra);
#pragma unroll
        for (int s = 0; s < 8; ++s) sts16(lB, tid + 256 * s, rb[s]);
        __syncthreads();
        if (kt < 15) {
            ra = BF16A ? ldg16(gab, astr * 2, (kt + 1) * 64, tid)
                       : ldg16_f32(gaf, astr, (kt + 1) * 32, tid);
#pragma unroll
            for (int s = 0; s < 8; ++s) rb[s] = ldg16(gb, 1024, (kt + 1) * 64, tid + 256 * s);
        }
        bf16x8 af[2];
#pragma unroll
        for (int mf = 0; mf < 2; ++mf)
            af[mf] = ldsfrag(lA, wm * 32 + mf * 16 + c16, hi);
#pragma unroll
        for (int nf = 0; nf < 16; ++nf) {
            bf16x8 bfr = ldsfrag(lB, wn * 256 + nf * 16 + c16, hi);
#pragma unroll
            for (int mf = 0; mf < 2; ++mf)
                acc[mf][nf] = __builtin_amdgcn_mfma_f32_16x16x32_bf16(af[mf], bfr, acc[mf][nf], 0, 0, 0);
        }
    }
#pragma unroll
    for (int nf = 0; nf < 16; ++nf) {
        float bj = bo[wn * 256 + nf * 16 + c16];
#pragma unroll
        for (int mf = 0; mf < 2; ++mf)
#pragma unroll
            for (int q = 0; q < 4; ++q)
                acc[mf][nf][q] = __expf(acc[mf][nf][q] + bj);
    }
#pragma unroll
    for (int mf = 0; mf < 2; ++mf)
#pragma unroll
        for (int q = 0; q < 4; ++q) {
            float s = 0.f;
#pragma unroll
            for (int nf = 0; nf < 16; ++nf) s += acc[mf][nf][q];
            s += __shfl_xor(s, 1); s += __shfl_xor(s, 2);
            s += __shfl_xor(s, 4); s += __shfl_xor(s, 8);
            if (c16 == 0) red[wm][wn][mf * 16 + hi * 4 + q] = s;
        }
    __syncthreads();
#pragma unroll
    for (int mf = 0; mf < 2; ++mf)
#pragma unroll
        for (int q = 0; q < 4; ++q) {
            int rl = mf * 16 + hi * 4 + q;
            float inv = 1.f / (red[wm][0][rl] + red[wm][1][rl]);
            int m = m0 + wm * 32 + rl;
            float* orow = out + (size_t)m * 512 + wn * 256 + c16;
#pragma unroll
            for (int nf = 0; nf < 16; ++nf) orow[nf * 16] = acc[mf][nf][q] * inv;
        }
}

// ---------------------------------------------------------------- launch
extern "C" void kernel_launch(void* const* d_in, const int* in_sizes, int n_in,
                              void* d_out, int out_size, void* d_ws, size_t ws_size,
                              hipStream_t stream) {
    const float* inputs = (const float*)d_in[0];
    const float* W_in   = (const float*)d_in[1];
    const float* b_in   = (const float*)d_in[2];
    const float* W_ih   = (const float*)d_in[3];
    const float* b_ih   = (const float*)d_in[4];
    const float* W_hh   = (const float*)d_in[5];
    const float* b_hh   = (const float*)d_in[6];
    const float* W_out  = (const float*)d_in[7];
    const float* b_out  = (const float*)d_in[8];

    float* out    = (float*)d_out;
    float* hidden = out + (size_t)126976 * 512;

    char* ws = (char*)d_ws;
    unsigned short* wih_b  = (unsigned short*)(ws);                 // 1.5 MB
    unsigned short* whh_b  = (unsigned short*)(ws + 1572864);       // 1.5 MB
    unsigned short* wout_b = (unsigned short*)(ws + 3145728);       // 0.5 MB
    unsigned short* x_b    = (unsigned short*)(ws + 3670016);       // 4 MB
    float*          gi     = (float*)(ws + 7864320);                // 25.2 MB
    const bool big = ws_size >= 163053568ULL;                       // hbf2 slab fits?
    unsigned short* hbf2   = (unsigned short*)(ws + 33030144);      // big: [126976,512] bf16
    unsigned short* hb0    = (unsigned short*)(ws + 33030144);      // small: ping-pong
    unsigned short* hb1    = (unsigned short*)(ws + 37224448);

    k_f32_to_bf16<<<768, 256, 0, stream>>>(W_ih, wih_b, 196608);
    k_f32_to_bf16<<<768, 256, 0, stream>>>(W_hh, whh_b, 196608);
    k_f32_to_bf16<<<256, 256, 0, stream>>>(W_out, wout_b, 65536);
    k_linear_in<<<8192, 256, 0, stream>>>(inputs, W_in, b_in, x_b);
    k_gemm_gi<<<dim3(32, 24), 256, 0, stream>>>(x_b, wih_b, b_ih, gi);

    for (int t = 0; t < 31; ++t) {
        const unsigned short* Hin;
        unsigned short* Hout;
        int hs, os;
        if (big) {
            Hin  = hbf2 + (size_t)(t > 0 ? t - 1 : 0) * 512;  hs = NTH;
            Hout = hbf2 + (size_t)t * 512;                     os = NTH;
        } else {
            Hin  = (t & 1) ? hb0 : hb1;  hs = 512;
            Hout = (t & 1) ? hb1 : hb0;  os = 512;
        }
        k_step<<<dim3(32, 16), 256, 0, stream>>>(Hin, hs, whh_b, gi, b_hh,
                                                 hidden, Hout, os, t);
    }
    // hbf2 viewed as [126976,512] row-major has row stride 512
    if (big) k_proj<true><<<1984, 256, 0, stream>>>(hbf2, 512, wout_b, b_out, out);
    else     k_proj<false><<<1984, 256, 0, stream>>>(hidden, 512, wout_b, b_out, out);
}

// Round 10
// 782.561 us; speedup vs baseline: 1.9354x; 1.9354x over previous
//
#include <hip/hip_runtime.h>

// GRUModel: B=4096, H=512, V=512, T=31, D_IN=14
// d_out = [probs: 4096*31*512 f32][hidden: 4096*31*512 f32]
#define NTH 15872   // 31*512

typedef __bf16 bf16x8 __attribute__((ext_vector_type(8)));
typedef float  f32x4  __attribute__((ext_vector_type(4)));

__device__ __forceinline__ unsigned short f2bf(float f) {
    unsigned u = __float_as_uint(f);
    u = u + 0x7fffu + ((u >> 16) & 1u);
    return (unsigned short)(u >> 16);
}
__device__ __forceinline__ float sigm(float x)  { return 1.f / (1.f + __expf(-x)); }
__device__ __forceinline__ float tanhf_(float x){ return 2.f / (1.f + __expf(-2.f * x)) - 1.f; }

// R1/R4/R8-proven LDS tile layout (64B rows, K=32 bf16): chunk ^= (r>>1)&3.
// NOTE: the 128B-row 'soff' layout was used only in R5/R9 — both regressions.
__device__ __forceinline__ int lds_off(int r, int kb) {
    return r * 64 + ((kb ^ ((r >> 1) & 3)) << 4);
}
__device__ __forceinline__ int4 ldg16(const char* g0, int stride, int kbyte, int c) {
    int r = c >> 2, kb = c & 3;
    return *(const int4*)(g0 + (size_t)r * stride + kbyte + kb * 16);
}
__device__ __forceinline__ void sts16(char* lds, int c, int4 v) {
    int r = c >> 2, kb = c & 3;
    *(int4*)(lds + lds_off(r, kb)) = v;
}
__device__ __forceinline__ bf16x8 ldsfrag(const char* lds, int row, int hi) {
    return *(const bf16x8*)(lds + lds_off(row, hi));
}
// load 8 f32 (stride in floats), round to bf16, pack to one 16B chunk
__device__ __forceinline__ int4 ldg16_f32(const float* g0, int stride, int koff, int c) {
    int r = c >> 2, kb = c & 3;
    const float4* p = (const float4*)(g0 + (size_t)r * stride + koff + kb * 8);
    float4 a = p[0], b = p[1];
    union { unsigned short us[8]; int4 v; } u;
    u.us[0]=f2bf(a.x); u.us[1]=f2bf(a.y); u.us[2]=f2bf(a.z); u.us[3]=f2bf(a.w);
    u.us[4]=f2bf(b.x); u.us[5]=f2bf(b.y); u.us[6]=f2bf(b.z); u.us[7]=f2bf(b.w);
    return u.v;
}

// ---------------------------------------------------------------- converts
__global__ void k_f32_to_bf16(const float* __restrict__ in,
                              unsigned short* __restrict__ out, int n4) {
    int i = blockIdx.x * 256 + threadIdx.x;
    if (i < n4) {
        float4 v = ((const float4*)in)[i];
        ushort4 o;
        o.x = f2bf(v.x); o.y = f2bf(v.y); o.z = f2bf(v.z); o.w = f2bf(v.w);
        ((ushort4*)out)[i] = o;
    }
}

// ---------------------------------------------------------------- x = inputs @ W_in.T + b_in  -> bf16
__global__ void k_linear_in(const float* __restrict__ inp,   // [4096,14]
                            const float* __restrict__ W,     // [512,14]
                            const float* __restrict__ bias,  // [512]
                            unsigned short* __restrict__ xb) // [4096,512] bf16
{
    int idx = blockIdx.x * 256 + threadIdx.x;   // b*512 + j
    int b = idx >> 9, j = idx & 511;
    const float* ir = inp + (size_t)b * 14;
    const float* wr = W + (size_t)j * 14;
    float acc = bias[j];
#pragma unroll
    for (int k = 0; k < 14; ++k) acc += ir[k] * wr[k];
    xb[idx] = f2bf(acc);
}

// ---------------------------------------------------------------- gi = x @ W_ih.T + b_ih (f32 out)
// R1-verbatim: BM=128, BN=64, BK=32, 256 thr = 4 waves (2x2), wave tile 64x32
__global__ __launch_bounds__(256) void k_gemm_gi(
    const unsigned short* __restrict__ A,   // [4096,512] bf16
    const unsigned short* __restrict__ W,   // [1536,512] bf16
    const float* __restrict__ bias,         // [1536]
    float* __restrict__ C)                  // [4096,1536]
{
    __shared__ __align__(16) char lA[128 * 64];
    __shared__ __align__(16) char lB[64 * 64];
    const int tid = threadIdx.x, lane = tid & 63, wid = tid >> 6;
    const int wm = wid >> 1, wn = wid & 1, hi = lane >> 4, c16 = lane & 15;
    const int m0 = blockIdx.x * 128, n0 = blockIdx.y * 64;
    const char* ga = (const char*)(A + (size_t)m0 * 512);
    const char* gb = (const char*)(W + (size_t)n0 * 512);
    f32x4 acc[4][2] = {};
    int4 ra0 = ldg16(ga, 1024, 0, tid);
    int4 ra1 = ldg16(ga, 1024, 0, tid + 256);
    int4 rb0 = ldg16(gb, 1024, 0, tid);
    for (int kt = 0; kt < 16; ++kt) {
        if (kt) __syncthreads();
        sts16(lA, tid, ra0); sts16(lA, tid + 256, ra1); sts16(lB, tid, rb0);
        __syncthreads();
        if (kt < 15) {
            int kb = (kt + 1) * 64;
            ra0 = ldg16(ga, 1024, kb, tid);
            ra1 = ldg16(ga, 1024, kb, tid + 256);
            rb0 = ldg16(gb, 1024, kb, tid);
        }
        bf16x8 af[4];
#pragma unroll
        for (int i = 0; i < 4; ++i) af[i] = ldsfrag(lA, wm * 64 + i * 16 + c16, hi);
#pragma unroll
        for (int j = 0; j < 2; ++j) {
            bf16x8 bfr = ldsfrag(lB, wn * 32 + j * 16 + c16, hi);
#pragma unroll
            for (int i = 0; i < 4; ++i)
                acc[i][j] = __builtin_amdgcn_mfma_f32_16x16x32_bf16(af[i], bfr, acc[i][j], 0, 0, 0);
        }
    }
#pragma unroll
    for (int i = 0; i < 4; ++i) {
        int m = m0 + wm * 64 + i * 16 + hi * 4;
#pragma unroll
        for (int j = 0; j < 2; ++j) {
            int n = n0 + wn * 32 + j * 16 + c16;
            float bj = bias[n];
#pragma unroll
            for (int q = 0; q < 4; ++q)
                C[(size_t)(m + q) * 1536 + n] = acc[i][j][q] + bj;
        }
    }
}

// ---------------------------------------------------------------- fused GRU step v5
// R8 config (BM=128, BN=32/gate, BK=32, grid 32x16 = 512 blocks -> 2/CU,
// 4 waves 2wm x 2wn, wave tile 64x16/gate, lds_off layout) with ONE change:
// two-buffer LDS -> ONE barrier per kt (16/step instead of 32).
// Iter kt: issue kt+1 loads; barrier; read buf[cur]+MFMA; write buf[cur^1].
// Disjoint buffers make the single barrier both visibility and anti-dep fence.
// Arithmetic & k-order unchanged -> bitwise-identical h trajectory.
__device__ __forceinline__ int4 ldg16B3v(const char* gW, int n0, int kbyte, int c) {
    int r = c >> 2, kb = c & 3;                     // r in [0,96): gate = r>>5
    int wrow = ((r >> 5) << 9) + n0 + (r & 31);     // W_hh row
    return *(const int4*)(gW + (size_t)wrow * 1024 + kbyte + kb * 16);
}

__global__ __launch_bounds__(256) void k_step(
    const unsigned short* __restrict__ Hin, int hstride,  // elems
    const unsigned short* __restrict__ Whh,   // [1536,512] bf16
    const float* __restrict__ gi,             // [4096,1536]
    const float* __restrict__ bhh,            // [1536]
    float* __restrict__ hidden,               // [4096, 15872] f32 (d_out region)
    unsigned short* __restrict__ Hout, int ostride,       // elems
    int t)
{
    __shared__ __align__(16) char lA[2][128 * 64];   // 2 x 8 KB
    __shared__ __align__(16) char lB[2][96 * 64];    // 2 x 6 KB
    const int tid = threadIdx.x, lane = tid & 63, wid = tid >> 6;
    const int wm = wid >> 1, wn = wid & 1, hi = lane >> 4, c16 = lane & 15;
    const int m0 = blockIdx.x * 128, n0 = blockIdx.y * 32;
    f32x4 acc[3][4] = {};
    if (t > 0) {
        const char* ga = (const char*)(Hin + (size_t)m0 * hstride);
        const int gas = hstride * 2;              // row stride bytes
        const char* gw = (const char*)Whh;
        int4 ra0 = ldg16(ga, gas, 0, tid);
        int4 ra1 = ldg16(ga, gas, 0, tid + 256);
        int4 rb0 = ldg16B3v(gw, n0, 0, tid);
        int4 rb1;
        if (tid < 128) rb1 = ldg16B3v(gw, n0, 0, tid + 256);
        // prologue: fill buf 0 (first barrier inside loop publishes it)
        sts16(lA[0], tid, ra0); sts16(lA[0], tid + 256, ra1);
        sts16(lB[0], tid, rb0);
        if (tid < 128) sts16(lB[0], tid + 256, rb1);
        for (int kt = 0; kt < 16; ++kt) {
            const int cur = kt & 1;
            if (kt < 15) {
                int kb = (kt + 1) * 64;
                ra0 = ldg16(ga, gas, kb, tid);
                ra1 = ldg16(ga, gas, kb, tid + 256);
                rb0 = ldg16B3v(gw, n0, kb, tid);
                if (tid < 128) rb1 = ldg16B3v(gw, n0, kb, tid + 256);
            }
            __syncthreads();   // publishes buf[cur] (written pre-loop or in kt-1)
            bf16x8 af[4];
#pragma unroll
            for (int i = 0; i < 4; ++i) af[i] = ldsfrag(lA[cur], wm * 64 + i * 16 + c16, hi);
#pragma unroll
            for (int g = 0; g < 3; ++g) {
                bf16x8 bfr = ldsfrag(lB[cur], g * 32 + wn * 16 + c16, hi);
#pragma unroll
                for (int i = 0; i < 4; ++i)
                    acc[g][i] = __builtin_amdgcn_mfma_f32_16x16x32_bf16(af[i], bfr, acc[g][i], 0, 0, 0);
            }
            if (kt < 15) {     // stage kt+1 into the other buffer (no barrier needed)
                sts16(lA[cur ^ 1], tid, ra0); sts16(lA[cur ^ 1], tid + 256, ra1);
                sts16(lB[cur ^ 1], tid, rb0);
                if (tid < 128) sts16(lB[cur ^ 1], tid + 256, rb1);
            }
        }
    }
    // epilogue: gate math (16 outputs/thread, r/z/n wave-local) — R8-verbatim
    const int n = n0 + wn * 16 + c16;              // gate-local column
    const float br = bhh[n], bz = bhh[512 + n], bn_ = bhh[1024 + n];
#pragma unroll
    for (int i = 0; i < 4; ++i) {
        int mB = m0 + wm * 64 + i * 16 + hi * 4;
#pragma unroll
        for (int q = 0; q < 4; ++q) {
            int m = mB + q;
            size_t gb0 = (size_t)m * 1536 + n;
            float pr = gi[gb0]        + acc[0][i][q] + br;
            float pz = gi[gb0 + 512]  + acc[1][i][q] + bz;
            float r  = sigm(pr);
            float z  = sigm(pz);
            float nn = tanhf_(gi[gb0 + 1024] + r * (acc[2][i][q] + bn_));
            float hold = (t > 0) ? hidden[(size_t)m * NTH + (size_t)(t - 1) * 512 + n] : 0.f;
            float hn = (1.f - z) * nn + z * hold;
            hidden[(size_t)m * NTH + (size_t)t * 512 + n] = hn;
            Hout[(size_t)m * ostride + n] = f2bf(hn);
        }
    }
}

// ---------------------------------------------------------------- projection + softmax (R4-verbatim)
// BM=64, BN=512 (full V), BK=32, 256 thr = 4 waves in 2x2; wave tile 32x256.
template<bool BF16A>
__global__ __launch_bounds__(256) void k_proj(
    const void* __restrict__ Aptr,          // bf16 or f32 [126976,512], row stride astr elems
    int astr,
    const unsigned short* __restrict__ Wo,  // [512,512] bf16
    const float* __restrict__ bo,
    float* __restrict__ out)                // [126976,512]
{
    __shared__ __align__(16) char lA[64 * 64];
    __shared__ __align__(16) char lB[512 * 64];
    __shared__ float red[2][2][32];
    const int tid = threadIdx.x, lane = tid & 63, wid = tid >> 6;
    const int wm = wid >> 1, wn = wid & 1, hi = lane >> 4, c16 = lane & 15;
    const int m0 = blockIdx.x * 64;
    const char*  gab = (const char*)Aptr  + (size_t)m0 * astr * 2;
    const float* gaf = (const float*)Aptr + (size_t)m0 * astr;
    const char*  gb  = (const char*)Wo;
    f32x4 acc[2][16] = {};
    int4 ra = BF16A ? ldg16(gab, astr * 2, 0, tid) : ldg16_f32(gaf, astr, 0, tid);
    int4 rb[8];
#pragma unroll
    for (int s = 0; s < 8; ++s) rb[s] = ldg16(gb, 1024, 0, tid + 256 * s);
    for (int kt = 0; kt < 16; ++kt) {
        if (kt) __syncthreads();
        sts16(lA, tid, ra);
#pragma unroll
        for (int s = 0; s < 8; ++s) sts16(lB, tid + 256 * s, rb[s]);
        __syncthreads();
        if (kt < 15) {
            ra = BF16A ? ldg16(gab, astr * 2, (kt + 1) * 64, tid)
                       : ldg16_f32(gaf, astr, (kt + 1) * 32, tid);
#pragma unroll
            for (int s = 0; s < 8; ++s) rb[s] = ldg16(gb, 1024, (kt + 1) * 64, tid + 256 * s);
        }
        bf16x8 af[2];
#pragma unroll
        for (int mf = 0; mf < 2; ++mf)
            af[mf] = ldsfrag(lA, wm * 32 + mf * 16 + c16, hi);
#pragma unroll
        for (int nf = 0; nf < 16; ++nf) {
            bf16x8 bfr = ldsfrag(lB, wn * 256 + nf * 16 + c16, hi);
#pragma unroll
            for (int mf = 0; mf < 2; ++mf)
                acc[mf][nf] = __builtin_amdgcn_mfma_f32_16x16x32_bf16(af[mf], bfr, acc[mf][nf], 0, 0, 0);
        }
    }
#pragma unroll
    for (int nf = 0; nf < 16; ++nf) {
        float bj = bo[wn * 256 + nf * 16 + c16];
#pragma unroll
        for (int mf = 0; mf < 2; ++mf)
#pragma unroll
            for (int q = 0; q < 4; ++q)
                acc[mf][nf][q] = __expf(acc[mf][nf][q] + bj);
    }
#pragma unroll
    for (int mf = 0; mf < 2; ++mf)
#pragma unroll
        for (int q = 0; q < 4; ++q) {
            float s = 0.f;
#pragma unroll
            for (int nf = 0; nf < 16; ++nf) s += acc[mf][nf][q];
            s += __shfl_xor(s, 1); s += __shfl_xor(s, 2);
            s += __shfl_xor(s, 4); s += __shfl_xor(s, 8);
            if (c16 == 0) red[wm][wn][mf * 16 + hi * 4 + q] = s;
        }
    __syncthreads();
#pragma unroll
    for (int mf = 0; mf < 2; ++mf)
#pragma unroll
        for (int q = 0; q < 4; ++q) {
            int rl = mf * 16 + hi * 4 + q;
            float inv = 1.f / (red[wm][0][rl] + red[wm][1][rl]);
            int m = m0 + wm * 32 + rl;
            float* orow = out + (size_t)m * 512 + wn * 256 + c16;
#pragma unroll
            for (int nf = 0; nf < 16; ++nf) orow[nf * 16] = acc[mf][nf][q] * inv;
        }
}

// ---------------------------------------------------------------- launch
extern "C" void kernel_launch(void* const* d_in, const int* in_sizes, int n_in,
                              void* d_out, int out_size, void* d_ws, size_t ws_size,
                              hipStream_t stream) {
    const float* inputs = (const float*)d_in[0];
    const float* W_in   = (const float*)d_in[1];
    const float* b_in   = (const float*)d_in[2];
    const float* W_ih   = (const float*)d_in[3];
    const float* b_ih   = (const float*)d_in[4];
    const float* W_hh   = (const float*)d_in[5];
    const float* b_hh   = (const float*)d_in[6];
    const float* W_out  = (const float*)d_in[7];
    const float* b_out  = (const float*)d_in[8];

    float* out    = (float*)d_out;
    float* hidden = out + (size_t)126976 * 512;

    char* ws = (char*)d_ws;
    unsigned short* wih_b  = (unsigned short*)(ws);                 // 1.5 MB
    unsigned short* whh_b  = (unsigned short*)(ws + 1572864);       // 1.5 MB
    unsigned short* wout_b = (unsigned short*)(ws + 3145728);       // 0.5 MB
    unsigned short* x_b    = (unsigned short*)(ws + 3670016);       // 4 MB
    float*          gi     = (float*)(ws + 7864320);                // 25.2 MB
    const bool big = ws_size >= 163053568ULL;                       // hbf2 slab fits?
    unsigned short* hbf2   = (unsigned short*)(ws + 33030144);      // big: [126976,512] bf16
    unsigned short* hb0    = (unsigned short*)(ws + 33030144);      // small: ping-pong
    unsigned short* hb1    = (unsigned short*)(ws + 37224448);

    k_f32_to_bf16<<<768, 256, 0, stream>>>(W_ih, wih_b, 196608);
    k_f32_to_bf16<<<768, 256, 0, stream>>>(W_hh, whh_b, 196608);
    k_f32_to_bf16<<<256, 256, 0, stream>>>(W_out, wout_b, 65536);
    k_linear_in<<<8192, 256, 0, stream>>>(inputs, W_in, b_in, x_b);
    k_gemm_gi<<<dim3(32, 24), 256, 0, stream>>>(x_b, wih_b, b_ih, gi);

    for (int t = 0; t < 31; ++t) {
        const unsigned short* Hin;
        unsigned short* Hout;
        int hs, os;
        if (big) {
            Hin  = hbf2 + (size_t)(t > 0 ? t - 1 : 0) * 512;  hs = NTH;
            Hout = hbf2 + (size_t)t * 512;                     os = NTH;
        } else {
            Hin  = (t & 1) ? hb0 : hb1;  hs = 512;
            Hout = (t & 1) ? hb1 : hb0;  os = 512;
        }
        k_step<<<dim3(32, 16), 256, 0, stream>>>(Hin, hs, whh_b, gi, b_hh,
                                                 hidden, Hout, os, t);
    }
    // hbf2 viewed as [126976,512] row-major has row stride 512
    if (big) k_proj<true><<<1984, 256, 0, stream>>>(hbf2, 512, wout_b, b_out, out);
    else     k_proj<false><<<1984, 256, 0, stream>>>(hidden, 512, wout_b, b_out, out);
}